// Round 2
// baseline (704.843 us; speedup 1.0000x reference)
//
#include <hip/hip_runtime.h>

typedef __bf16 bf16_t;
typedef bf16_t bf16x8 __attribute__((ext_vector_type(8)));
typedef float f32x4 __attribute__((ext_vector_type(4)));

#define BATCH 4
#define SEQ 4096
#define EMBED 512
#define MTOT (BATCH * SEQ)

// ---------------------------------------------------------------------------
// Stage 1: q = cos(x + theta) @ W^T + b   (M=16384, N=512, K=512), fp32 in,
// bf16 out. Writes qrow [16384][512] AND qt [4][512][4096] (per-batch
// transpose) so the attention kernel can feed V fragments in MFMA B-layout.
// ---------------------------------------------------------------------------
__global__ __launch_bounds__(256, 2) void gemm_q_kernel(
    const float* __restrict__ x, const float* __restrict__ theta,
    const float* __restrict__ W, const float* __restrict__ bias,
    bf16_t* __restrict__ qrow, bf16_t* __restrict__ qt)
{
    __shared__ alignas(16) bf16_t As[64][40];   // 64 rows x BK=32 (+8 pad)
    __shared__ alignas(16) bf16_t Ws[64][40];
    __shared__ float th[64];

    const int t    = threadIdx.x;
    const int m0   = blockIdx.x * 64;
    const int n0   = blockIdx.y * 64;
    const int lane = t & 63;
    const int wave = t >> 6;
    const int l15  = lane & 15;
    const int quad = lane >> 4;

    if (t < 64) th[t] = theta[t];

    f32x4 acc[4];
#pragma unroll
    for (int n = 0; n < 4; ++n) acc[n] = (f32x4){0.f, 0.f, 0.f, 0.f};

    const int srow = t >> 2;   // 0..63
    const int sseg = t & 3;    // 0..3 (8 floats each -> 32 k)

    for (int kk = 0; kk < 16; ++kk) {
        const int k0 = kk * 32;
        __syncthreads();
        // stage A = bf16(cos(x + theta)) and bf16(W)
        {
            const float* xp = &x[(m0 + srow) * 512 + k0 + sseg * 8];
            const float* wp = &W[(n0 + srow) * 512 + k0 + sseg * 8];
            float4 x0 = *(const float4*)xp;
            float4 x1 = *(const float4*)(xp + 4);
            float4 w0 = *(const float4*)wp;
            float4 w1 = *(const float4*)(wp + 4);
            float xv[8] = {x0.x, x0.y, x0.z, x0.w, x1.x, x1.y, x1.z, x1.w};
            float wv[8] = {w0.x, w0.y, w0.z, w0.w, w1.x, w1.y, w1.z, w1.w};
            bf16x8 av, bv;
#pragma unroll
            for (int j = 0; j < 8; ++j) {
                av[j] = (bf16_t)__cosf(xv[j] + th[(k0 + sseg * 8 + j) & 63]);
                bv[j] = (bf16_t)wv[j];
            }
            *(bf16x8*)&As[srow][sseg * 8] = av;
            *(bf16x8*)&Ws[srow][sseg * 8] = bv;
        }
        __syncthreads();
        // A-frag: A[m=l15][k=quad*8+j]; B-frag: W[n=l15][k=quad*8+j]
        bf16x8 af = *(const bf16x8*)&As[wave * 16 + l15][quad * 8];
#pragma unroll
        for (int n = 0; n < 4; ++n) {
            bf16x8 bfr = *(const bf16x8*)&Ws[n * 16 + l15][quad * 8];
            acc[n] = __builtin_amdgcn_mfma_f32_16x16x32_bf16(af, bfr, acc[n], 0, 0, 0);
        }
    }

    // epilogue: C/D layout row = quad*4+reg, col = lane&15
#pragma unroll
    for (int n = 0; n < 4; ++n) {
        const int col = n0 + n * 16 + l15;
        const float bv = bias[col];
#pragma unroll
        for (int r = 0; r < 4; ++r) {
            const int row = m0 + wave * 16 + quad * 4 + r;
            bf16_t qv = (bf16_t)(acc[n][r] + bv);
            qrow[row * 512 + col] = qv;
            const int b = row >> 12;
            const int i = row & 4095;
            qt[((b * 512 + col) << 12) + i] = qv;
        }
    }
}

// ---------------------------------------------------------------------------
// Stage 2: flash attention, Q=K=V=q, scale=1/8, full softmax over 4096 keys.
// Grid: (64 q-tiles, 4 batches), 256 threads. Br=64 (wave owns 16 rows),
// Bc=32. LDS union: Ks[32][520] (QK phase) / Vt[512][40] (PV phase).
// Output written in fp32 (reference output dtype).
// ---------------------------------------------------------------------------
__global__ __launch_bounds__(256, 1) void flash_kernel(
    const bf16_t* __restrict__ q, const bf16_t* __restrict__ qt,
    float* __restrict__ out)
{
    __shared__ alignas(16) bf16_t smem[20480];   // max(32*520, 512*40) shorts
    __shared__ alignas(16) bf16_t Ps[4][16][40]; // per-wave P tile (16 x 32)

    const int t    = threadIdx.x;
    const int lane = t & 63;
    const int wave = t >> 6;
    const int l15  = lane & 15;
    const int quad = lane >> 4;

    const int batch = blockIdx.y;
    const int q0    = blockIdx.x * 64;
    const bf16_t* qb  = q  + (size_t)batch * SEQ * EMBED;
    const bf16_t* qtb = qt + (size_t)batch * EMBED * SEQ;

    // preload Q fragments: A[m=l15][k = kf*32 + quad*8 + j], 16 frags = 512 d
    bf16x8 aQ[16];
    {
        const int row = q0 + wave * 16 + l15;
#pragma unroll
        for (int kf = 0; kf < 16; ++kf)
            aQ[kf] = *(const bf16x8*)&qb[row * 512 + kf * 32 + quad * 8];
    }

    f32x4 O[32];
#pragma unroll
    for (int et = 0; et < 32; ++et) O[et] = (f32x4){0.f, 0.f, 0.f, 0.f};
    float mrow[4], lrow[4];
#pragma unroll
    for (int r = 0; r < 4; ++r) { mrow[r] = -1e30f; lrow[r] = 0.f; }

    for (int it = 0; it < 128; ++it) {
        const int k0 = it * 32;
        __syncthreads();
        // ---- phase 1: stage K tile [32 keys][512 dims] row-major ----
        {
#pragma unroll
            for (int cc = 0; cc < 8; ++cc) {
                int chunk = t + 256 * cc;          // 0..2047
                int r = chunk >> 6;                // key row 0..31
                int c = (chunk & 63) * 8;          // dim offset 0..504
                bf16x8 v = *(const bf16x8*)&qb[(k0 + r) * 512 + c];
                *(bf16x8*)&smem[r * 520 + c] = v;
            }
        }
        __syncthreads();
        // ---- S = Q K^T (2 key-subtiles of 16) ----
        f32x4 s[2];
#pragma unroll
        for (int n = 0; n < 2; ++n) {
            f32x4 a = (f32x4){0.f, 0.f, 0.f, 0.f};
#pragma unroll
            for (int kf = 0; kf < 16; ++kf) {
                bf16x8 bk = *(const bf16x8*)&smem[(n * 16 + l15) * 520 + kf * 32 + quad * 8];
                a = __builtin_amdgcn_mfma_f32_16x16x32_bf16(aQ[kf], bk, a, 0, 0, 0);
            }
            s[n] = a;
        }
        // ---- online softmax (row = quad*4 + r, cols = n*16 + l15) ----
        float pv[2][4];
#pragma unroll
        for (int r = 0; r < 4; ++r) {
            float s0 = s[0][r] * 0.125f;
            float s1 = s[1][r] * 0.125f;
            float mx = fmaxf(s0, s1);
#pragma unroll
            for (int d = 1; d < 16; d <<= 1) mx = fmaxf(mx, __shfl_xor(mx, d));
            float mnew  = fmaxf(mrow[r], mx);
            float alpha = __expf(mrow[r] - mnew);
            float p0 = __expf(s0 - mnew), p1 = __expf(s1 - mnew);
            float rs = p0 + p1;
#pragma unroll
            for (int d = 1; d < 16; d <<= 1) rs += __shfl_xor(rs, d);
            lrow[r] = alpha * lrow[r] + rs;
            mrow[r] = mnew;
            pv[0][r] = p0; pv[1][r] = p1;
#pragma unroll
            for (int et = 0; et < 32; ++et) O[et][r] *= alpha;
        }
        // write P (C-layout) to LDS in A-layout-friendly row-major form
#pragma unroll
        for (int n = 0; n < 2; ++n)
#pragma unroll
            for (int r = 0; r < 4; ++r)
                Ps[wave][quad * 4 + r][n * 16 + l15] = (bf16_t)pv[n][r];
        __syncthreads();
        // ---- phase 2: stage V^T tile [512 e][32 keys] from qt ----
        {
#pragma unroll
            for (int cc = 0; cc < 8; ++cc) {
                int chunk = t + 256 * cc;          // 0..2047
                int e = chunk >> 2;                // 0..511
                int c = (chunk & 3) * 8;           // 0..24
                bf16x8 v = *(const bf16x8*)&qtb[e * 4096 + k0 + c];
                *(bf16x8*)&smem[e * 40 + c] = v;
            }
        }
        __syncthreads();
        // ---- O += P V : A = P[m=l15][k=quad*8+j], B = Vt[n=et*16+l15][k] ----
        bf16x8 pa = *(const bf16x8*)&Ps[wave][l15][quad * 8];
#pragma unroll
        for (int et = 0; et < 32; ++et) {
            bf16x8 bv = *(const bf16x8*)&smem[(et * 16 + l15) * 40 + quad * 8];
            O[et] = __builtin_amdgcn_mfma_f32_16x16x32_bf16(pa, bv, O[et], 0, 0, 0);
        }
    }

    // epilogue: out[row][e] = O / l  (fp32 output)
    const int orow = batch * SEQ + q0 + wave * 16 + quad * 4;
#pragma unroll
    for (int et = 0; et < 32; ++et) {
#pragma unroll
        for (int r = 0; r < 4; ++r) {
            float v = O[et][r] / lrow[r];
            out[(size_t)(orow + r) * 512 + et * 16 + l15] = v;
        }
    }
}

extern "C" void kernel_launch(void* const* d_in, const int* in_sizes, int n_in,
                              void* d_out, int out_size, void* d_ws, size_t ws_size,
                              hipStream_t stream) {
    const float* x     = (const float*)d_in[0];
    const float* theta = (const float*)d_in[1];
    const float* W     = (const float*)d_in[2];
    const float* bias  = (const float*)d_in[3];
    float* out   = (float*)d_out;
    bf16_t* qrow = (bf16_t*)d_ws;                       // [16384][512] bf16
    bf16_t* qt   = qrow + (size_t)MTOT * EMBED;         // [4][512][4096] bf16

    dim3 g1(MTOT / 64, EMBED / 64);   // 256 x 8
    gemm_q_kernel<<<g1, dim3(256), 0, stream>>>(x, theta, W, bias, qrow, qt);

    dim3 g2(SEQ / 64, BATCH);         // 64 x 4
    flash_kernel<<<g2, dim3(256), 0, stream>>>(qrow, qt, out);
}

// Round 3
// 525.691 us; speedup vs baseline: 1.3408x; 1.3408x over previous
//
#include <hip/hip_runtime.h>

typedef __bf16 bf16_t;
typedef bf16_t bf16x8 __attribute__((ext_vector_type(8)));
typedef bf16_t bf16x4 __attribute__((ext_vector_type(4)));
typedef float f32x4 __attribute__((ext_vector_type(4)));

#define BATCH 4
#define SEQ 4096
#define EMBED 512
#define MTOT (BATCH * SEQ)
#define NSPLIT 2

// global row-sum-of-exp accumulator (64 KB static device mem; zeroed in gemm)
__device__ float Lacc_g[MTOT];

// ---------------------------------------------------------------------------
// Stage 1: q = cos(x + theta) @ W^T + b  (M=16384, N=512, K=512) fp32->bf16.
// m-tile 32, FULL n=512 per block (x read once). grid 512 -> 2 blocks/CU.
// Waves split n: wave owns 128 cols. Writes qrow[16384][512] and per-batch
// transpose qt[4][512][4096]. Also zeroes Lacc_g.
// ---------------------------------------------------------------------------
__global__ __launch_bounds__(256, 2) void gemm_q_kernel(
    const float* __restrict__ x, const float* __restrict__ theta,
    const float* __restrict__ W, const float* __restrict__ bias,
    bf16_t* __restrict__ qrow, bf16_t* __restrict__ qt)
{
    __shared__ alignas(16) bf16_t As[32][40];
    __shared__ alignas(16) bf16_t Ws[512][40];
    __shared__ float th[64];

    const int t    = threadIdx.x;
    const int m0   = blockIdx.x * 32;
    const int lane = t & 63;
    const int wave = t >> 6;
    const int l15  = lane & 15;
    const int quad = lane >> 4;

    if (t < 64) th[t] = theta[t];
    // zero Lacc_g (blocks 0..15 cover 16384 floats); gemm completes before flash
    if (blockIdx.x < 16)
        ((float4*)Lacc_g)[blockIdx.x * 256 + t] = make_float4(0.f, 0.f, 0.f, 0.f);

    f32x4 acc[2][8];
#pragma unroll
    for (int m = 0; m < 2; ++m)
#pragma unroll
        for (int n = 0; n < 8; ++n) acc[m][n] = (f32x4){0.f, 0.f, 0.f, 0.f};

    const int arow = t >> 3;          // 0..31
    const int aseg = t & 7;           // 0..7 (4 floats each)
    const int wrow = t >> 2;          // 0..63 (+64j)
    const int wseg = t & 3;           // 0..3 (8 floats each)

    for (int kk = 0; kk < 16; ++kk) {
        const int k0 = kk * 32;
        __syncthreads();
        {   // stage A = bf16(cos(x+theta)): 32 rows x 32 k
            float4 xv = *(const float4*)&x[(m0 + arow) * 512 + k0 + aseg * 4];
            bf16x4 av;
            av[0] = (bf16_t)__cosf(xv.x + th[(k0 + aseg * 4 + 0) & 63]);
            av[1] = (bf16_t)__cosf(xv.y + th[(k0 + aseg * 4 + 1) & 63]);
            av[2] = (bf16_t)__cosf(xv.z + th[(k0 + aseg * 4 + 2) & 63]);
            av[3] = (bf16_t)__cosf(xv.w + th[(k0 + aseg * 4 + 3) & 63]);
            *(bf16x4*)&As[arow][aseg * 4] = av;
            // stage W: 512 rows x 32 k
#pragma unroll
            for (int j = 0; j < 8; ++j) {
                const int row = wrow + 64 * j;
                const float* wp = &W[row * 512 + k0 + wseg * 8];
                float4 w0 = *(const float4*)wp;
                float4 w1 = *(const float4*)(wp + 4);
                bf16x8 bv;
                bv[0] = (bf16_t)w0.x; bv[1] = (bf16_t)w0.y;
                bv[2] = (bf16_t)w0.z; bv[3] = (bf16_t)w0.w;
                bv[4] = (bf16_t)w1.x; bv[5] = (bf16_t)w1.y;
                bv[6] = (bf16_t)w1.z; bv[7] = (bf16_t)w1.w;
                *(bf16x8*)&Ws[row][wseg * 8] = bv;
            }
        }
        __syncthreads();
        bf16x8 af[2];
#pragma unroll
        for (int m = 0; m < 2; ++m)
            af[m] = *(const bf16x8*)&As[m * 16 + l15][quad * 8];
#pragma unroll
        for (int n = 0; n < 8; ++n) {
            bf16x8 bfr = *(const bf16x8*)&Ws[wave * 128 + n * 16 + l15][quad * 8];
#pragma unroll
            for (int m = 0; m < 2; ++m)
                acc[m][n] = __builtin_amdgcn_mfma_f32_16x16x32_bf16(af[m], bfr, acc[m][n], 0, 0, 0);
        }
    }

    // epilogue: row = quad*4+r, col = wave*128 + n*16 + l15
#pragma unroll
    for (int n = 0; n < 8; ++n) {
        const int col = wave * 128 + n * 16 + l15;
        const float bv = bias[col];
#pragma unroll
        for (int m = 0; m < 2; ++m) {
            const int row0 = m0 + m * 16 + quad * 4;
            bf16x4 pack;
#pragma unroll
            for (int r = 0; r < 4; ++r) {
                bf16_t qv = (bf16_t)(acc[m][n][r] + bv);
                qrow[(row0 + r) * 512 + col] = qv;
                pack[r] = qv;
            }
            const int b = row0 >> 12;
            const int i0 = row0 & 4095;
            *(bf16x4*)&qt[((size_t)(b * 512 + col) << 12) + i0] = pack;
        }
    }
}

// ---------------------------------------------------------------------------
// Stage 2: attention with NO online max (scores bounded << 88, exp safe in
// fp32). Q=K=V=q, scale=1/8. Br=64, Bc=32, KV-split 2 -> grid 512.
// QK: waves split rows (wave = m-tile, aQ in regs). PV: waves split e
// (128 each), P shared via LDS. Unnormalized O atomicAdd'ed into out (fp32),
// row exp-sums into Lacc_g; separate normalize pass divides.
// ---------------------------------------------------------------------------
__global__ __launch_bounds__(256, 2) void flash_kernel(
    const bf16_t* __restrict__ q, const bf16_t* __restrict__ qt,
    float* __restrict__ out)
{
    __shared__ alignas(16) bf16_t smem[20480];   // K: 32x520 / Vt: 512x40 union
    __shared__ alignas(16) bf16_t Ps[4][16][40]; // P: 4 m-tiles x 16 rows x 32

    const int t    = threadIdx.x;
    const int lane = t & 63;
    const int wave = t >> 6;
    const int l15  = lane & 15;
    const int quad = lane >> 4;

    const int batch = blockIdx.y;
    const int q0    = blockIdx.x * 64;
    const int kbase = blockIdx.z * (SEQ / NSPLIT);
    const bf16_t* qb  = q  + (size_t)batch * SEQ * EMBED;
    const bf16_t* qtb = qt + (size_t)batch * EMBED * SEQ;

    // Q fragments (row role): A[m=l15][k=kf*32+quad*8+j]
    bf16x8 aQ[16];
    {
        const int row = q0 + wave * 16 + l15;
#pragma unroll
        for (int kf = 0; kf < 16; ++kf)
            aQ[kf] = *(const bf16x8*)&qb[row * 512 + kf * 32 + quad * 8];
    }

    f32x4 O[4][8];   // e role: [m-tile][n], cols = wave*128 + n*16 + l15
#pragma unroll
    for (int m = 0; m < 4; ++m)
#pragma unroll
        for (int n = 0; n < 8; ++n) O[m][n] = (f32x4){0.f, 0.f, 0.f, 0.f};
    float lpart[4] = {0.f, 0.f, 0.f, 0.f};

    for (int it = 0; it < SEQ / NSPLIT / 32; ++it) {
        const int k0 = kbase + it * 32;
        __syncthreads();
        // stage K tile [32 keys][512 dims]
#pragma unroll
        for (int cc = 0; cc < 8; ++cc) {
            int chunk = t + 256 * cc;
            int r = chunk >> 6;
            int c = (chunk & 63) * 8;
            *(bf16x8*)&smem[r * 520 + c] = *(const bf16x8*)&qb[(k0 + r) * 512 + c];
        }
        __syncthreads();
        // S = Q K^T (row role): 2 key-subtiles
        f32x4 s[2];
#pragma unroll
        for (int n = 0; n < 2; ++n) {
            f32x4 a = (f32x4){0.f, 0.f, 0.f, 0.f};
#pragma unroll
            for (int kf = 0; kf < 16; ++kf) {
                bf16x8 bk = *(const bf16x8*)&smem[(n * 16 + l15) * 520 + kf * 32 + quad * 8];
                a = __builtin_amdgcn_mfma_f32_16x16x32_bf16(aQ[kf], bk, a, 0, 0, 0);
            }
            s[n] = a;
        }
        // P = exp(s/8)  (no max subtraction needed; see header comment)
#pragma unroll
        for (int r = 0; r < 4; ++r) {
            float p0 = __expf(s[0][r] * 0.125f);
            float p1 = __expf(s[1][r] * 0.125f);
            bf16_t b0 = (bf16_t)p0, b1 = (bf16_t)p1;
            lpart[r] += (float)b0 + (float)b1;    // match bf16-rounded P
            Ps[wave][quad * 4 + r][l15]      = b0;
            Ps[wave][quad * 4 + r][16 + l15] = b1;
        }
        __syncthreads();
        // stage V^T tile [512 e][32 keys]
#pragma unroll
        for (int cc = 0; cc < 8; ++cc) {
            int chunk = t + 256 * cc;
            int e = chunk >> 2;
            int c = (chunk & 3) * 8;
            *(bf16x8*)&smem[e * 40 + c] = *(const bf16x8*)&qtb[e * 4096 + k0 + c];
        }
        __syncthreads();
        // O += P V  (e role): A = Ps[m][l15][quad*8], B = Vt[e][quad*8]
        bf16x8 pa[4];
#pragma unroll
        for (int m = 0; m < 4; ++m)
            pa[m] = *(const bf16x8*)&Ps[m][l15][quad * 8];
#pragma unroll
        for (int n = 0; n < 8; ++n) {
            bf16x8 bv = *(const bf16x8*)&smem[(wave * 128 + n * 16 + l15) * 40 + quad * 8];
#pragma unroll
            for (int m = 0; m < 4; ++m)
                O[m][n] = __builtin_amdgcn_mfma_f32_16x16x32_bf16(pa[m], bv, O[m][n], 0, 0, 0);
        }
    }

    // row exp-sums (row role): reduce lpart over l15, one atomic per row
#pragma unroll
    for (int r = 0; r < 4; ++r) {
        float ls = lpart[r];
#pragma unroll
        for (int d = 1; d < 16; d <<= 1) ls += __shfl_xor(ls, d);
        if (l15 == 0)
            atomicAdd(&Lacc_g[batch * SEQ + q0 + wave * 16 + quad * 4 + r], ls);
    }
    // unnormalized O (e role): atomicAdd into out
#pragma unroll
    for (int m = 0; m < 4; ++m)
#pragma unroll
        for (int r = 0; r < 4; ++r) {
            const size_t row = (size_t)batch * SEQ + q0 + m * 16 + quad * 4 + r;
#pragma unroll
            for (int n = 0; n < 8; ++n)
                atomicAdd(&out[row * 512 + wave * 128 + n * 16 + l15], O[m][n][r]);
        }
}

// out[row][e] /= Lacc_g[row]
__global__ __launch_bounds__(256) void norm_kernel(float* __restrict__ out)
{
    const int idx = blockIdx.x * 256 + threadIdx.x;   // float4 index
    float4 v = ((float4*)out)[idx];
    const float inv = 1.0f / Lacc_g[idx >> 7];
    v.x *= inv; v.y *= inv; v.z *= inv; v.w *= inv;
    ((float4*)out)[idx] = v;
}

extern "C" void kernel_launch(void* const* d_in, const int* in_sizes, int n_in,
                              void* d_out, int out_size, void* d_ws, size_t ws_size,
                              hipStream_t stream) {
    const float* x     = (const float*)d_in[0];
    const float* theta = (const float*)d_in[1];
    const float* W     = (const float*)d_in[2];
    const float* bias  = (const float*)d_in[3];
    float* out   = (float*)d_out;
    bf16_t* qrow = (bf16_t*)d_ws;                       // [16384][512] bf16
    bf16_t* qt   = qrow + (size_t)MTOT * EMBED;         // [4][512][4096] bf16

    // out accumulates unnormalized O via atomics -> must start at zero
    hipMemsetAsync(out, 0, (size_t)MTOT * EMBED * sizeof(float), stream);

    gemm_q_kernel<<<dim3(MTOT / 32), dim3(256), 0, stream>>>(x, theta, W, bias, qrow, qt);

    flash_kernel<<<dim3(SEQ / 64, BATCH, NSPLIT), dim3(256), 0, stream>>>(qrow, qt, out);

    norm_kernel<<<dim3(MTOT * EMBED / 4 / 256), dim3(256), 0, stream>>>(out);
}

// Round 4
// 469.052 us; speedup vs baseline: 1.5027x; 1.1208x over previous
//
#include <hip/hip_runtime.h>

typedef __bf16 bf16_t;
typedef bf16_t bf16x8 __attribute__((ext_vector_type(8)));
typedef bf16_t bf16x4 __attribute__((ext_vector_type(4)));
typedef float f32x4 __attribute__((ext_vector_type(4)));

#define BATCH 4
#define SEQ 4096
#define EMBED 512
#define MTOT (BATCH * SEQ)
#define NSPLIT 4
#define KT (SEQ / NSPLIT)     // 1024 keys per block
#define FITERS (KT / 32)      // 32

__device__ float  Lacc_g[MTOT];        // row sum-of-exp accumulator
__device__ bf16_t Wbf_g[EMBED * EMBED]; // W pre-converted to bf16

// async global->LDS, 16 B per lane; lds base must be wave-uniform
__device__ __forceinline__ void async_copy16(const bf16_t* g, bf16_t* l) {
    __builtin_amdgcn_global_load_lds(
        (const __attribute__((address_space(1))) unsigned int*)g,
        (__attribute__((address_space(3))) unsigned int*)l, 16, 0, 0);
}

// ---------------------------------------------------------------------------
// Stage 0: W fp32 -> bf16 once (saves per-block cvt + half the W traffic)
// ---------------------------------------------------------------------------
__global__ __launch_bounds__(256) void cvt_w_kernel(const float* __restrict__ W) {
    const int i = (blockIdx.x * 256 + threadIdx.x) * 4;
    float4 v = *(const float4*)&W[i];
    bf16x4 o;
    o[0] = (bf16_t)v.x; o[1] = (bf16_t)v.y; o[2] = (bf16_t)v.z; o[3] = (bf16_t)v.w;
    *(bf16x4*)&Wbf_g[i] = o;
}

// ---------------------------------------------------------------------------
// Stage 1: q = cos(x + theta) @ W^T + b  (M=16384, N=512, K=512).
// m-tile 32, full n=512 per block, grid 512. Writes qrow + per-batch
// transpose qt. Also zeroes Lacc_g.
// ---------------------------------------------------------------------------
__global__ __launch_bounds__(256, 2) void gemm_q_kernel(
    const float* __restrict__ x, const float* __restrict__ theta,
    const float* __restrict__ bias,
    bf16_t* __restrict__ qrow, bf16_t* __restrict__ qt)
{
    __shared__ alignas(16) bf16_t As[32][40];
    __shared__ alignas(16) bf16_t Ws[512][40];
    __shared__ float th[64];

    const int t    = threadIdx.x;
    const int m0   = blockIdx.x * 32;
    const int lane = t & 63;
    const int wave = t >> 6;
    const int l15  = lane & 15;
    const int quad = lane >> 4;

    if (t < 64) th[t] = theta[t];
    if (blockIdx.x < 16)
        ((float4*)Lacc_g)[blockIdx.x * 256 + t] = make_float4(0.f, 0.f, 0.f, 0.f);

    f32x4 acc[2][8];
#pragma unroll
    for (int m = 0; m < 2; ++m)
#pragma unroll
        for (int n = 0; n < 8; ++n) acc[m][n] = (f32x4){0.f, 0.f, 0.f, 0.f};

    const int arow = t >> 3;          // 0..31
    const int aseg = t & 7;           // 0..7 (4 floats)

    for (int kk = 0; kk < 16; ++kk) {
        const int k0 = kk * 32;
        __syncthreads();
        {   // A = bf16(cos(x+theta)): 32 x 32
            float4 xv = *(const float4*)&x[(m0 + arow) * 512 + k0 + aseg * 4];
            bf16x4 av;
            av[0] = (bf16_t)__cosf(xv.x + th[(k0 + aseg * 4 + 0) & 63]);
            av[1] = (bf16_t)__cosf(xv.y + th[(k0 + aseg * 4 + 1) & 63]);
            av[2] = (bf16_t)__cosf(xv.z + th[(k0 + aseg * 4 + 2) & 63]);
            av[3] = (bf16_t)__cosf(xv.w + th[(k0 + aseg * 4 + 3) & 63]);
            *(bf16x4*)&As[arow][aseg * 4] = av;
        }
        // W (already bf16): 512 rows x 32 k
#pragma unroll
        for (int cc = 0; cc < 8; ++cc) {
            int idx = t + 256 * cc;       // 0..2047
            int row = idx >> 2;           // 0..511
            int seg = idx & 3;            // 8 shorts each
            *(bf16x8*)&Ws[row][seg * 8] =
                *(const bf16x8*)&Wbf_g[row * 512 + k0 + seg * 8];
        }
        __syncthreads();
        bf16x8 af[2];
#pragma unroll
        for (int m = 0; m < 2; ++m)
            af[m] = *(const bf16x8*)&As[m * 16 + l15][quad * 8];
#pragma unroll
        for (int n = 0; n < 8; ++n) {
            bf16x8 bfr = *(const bf16x8*)&Ws[wave * 128 + n * 16 + l15][quad * 8];
#pragma unroll
            for (int m = 0; m < 2; ++m)
                acc[m][n] = __builtin_amdgcn_mfma_f32_16x16x32_bf16(af[m], bfr, acc[m][n], 0, 0, 0);
        }
    }

#pragma unroll
    for (int n = 0; n < 8; ++n) {
        const int col = wave * 128 + n * 16 + l15;
        const float bv = bias[col];
#pragma unroll
        for (int m = 0; m < 2; ++m) {
            const int row0 = m0 + m * 16 + quad * 4;
            bf16x4 pack;
#pragma unroll
            for (int r = 0; r < 4; ++r) {
                bf16_t qv = (bf16_t)(acc[m][n][r] + bv);
                qrow[(row0 + r) * 512 + col] = qv;
                pack[r] = qv;
            }
            const int b  = row0 >> 12;
            const int i0 = row0 & 4095;
            *(bf16x4*)&qt[((size_t)(b * 512 + col) << 12) + i0] = pack;
        }
    }
}

// ---------------------------------------------------------------------------
// Stage 2: attention, no online max (scores bounded << 88). Br=64, Bc=32,
// KV-split 4 -> grid 1024. 2 barriers/iter: K staged via async
// global_load_lds (issued after P-barrier, lands during PV), V fragments
// read DIRECTLY from global qt (L2-served, no barrier gating -> MFMA/load
// interleave). XCD-aware remap: resident blocks per XCD share one
// (batch,ksplit) 2 MB working set.
// ---------------------------------------------------------------------------
__global__ __launch_bounds__(256, 2) void flash_kernel(
    const bf16_t* __restrict__ q, const bf16_t* __restrict__ qt,
    float* __restrict__ out)
{
    __shared__ alignas(16) bf16_t Ks[32][520];   // 33280 B
    __shared__ alignas(16) bf16_t Ps[4][16][40]; // 5120 B

    const int t    = threadIdx.x;
    const int lane = t & 63;
    const int wave = t >> 6;
    const int l15  = lane & 15;
    const int quad = lane >> 4;

    // work remap: xcd = blockIdx % 8 (heuristic, perf-only)
    const int L      = blockIdx.x;          // 0..1023
    const int xcd    = L & 7;
    const int slot   = L >> 3;              // 0..127
    const int g      = xcd + 8 * (slot >> 6); // group 0..15 = (batch,ksplit)
    const int qtile  = slot & 63;
    const int batch  = g >> 2;
    const int ksplit = g & 3;

    const int q0    = qtile * 64;
    const int kbase = ksplit * KT;
    const bf16_t* qb  = q  + (size_t)batch * SEQ * EMBED;
    const bf16_t* qtb = qt + (size_t)batch * EMBED * SEQ;

    // Q fragments: A[m=l15][k=kf*32+quad*8+j]
    bf16x8 aQ[16];
    {
        const int row = q0 + wave * 16 + l15;
#pragma unroll
        for (int kf = 0; kf < 16; ++kf)
            aQ[kf] = *(const bf16x8*)&qb[row * 512 + kf * 32 + quad * 8];
    }

    f32x4 O[4][8];
#pragma unroll
    for (int m = 0; m < 4; ++m)
#pragma unroll
        for (int n = 0; n < 8; ++n) O[m][n] = (f32x4){0.f, 0.f, 0.f, 0.f};
    float lpart[4] = {0.f, 0.f, 0.f, 0.f};

    // issue K(0): wave stages rows {cc*4+wave}, 1024 B each (lane*16 auto)
#pragma unroll
    for (int cc = 0; cc < 8; ++cc) {
        const int r = cc * 4 + wave;
        async_copy16(&qb[(size_t)(kbase + r) * 512 + lane * 8], &Ks[r][0]);
    }

    for (int it = 0; it < FITERS; ++it) {
        const int k0 = kbase + it * 32;
        __syncthreads();   // B1: Ks(it) ready (drains vmcnt); Ps(it-1) reads done
        // ---- QK: S = Q K^T ----
        f32x4 s[2];
#pragma unroll
        for (int n = 0; n < 2; ++n) {
            f32x4 a = (f32x4){0.f, 0.f, 0.f, 0.f};
#pragma unroll
            for (int kf = 0; kf < 16; ++kf) {
                bf16x8 bk = *(const bf16x8*)&Ks[n * 16 + l15][kf * 32 + quad * 8];
                a = __builtin_amdgcn_mfma_f32_16x16x32_bf16(aQ[kf], bk, a, 0, 0, 0);
            }
            s[n] = a;
        }
        // ---- P = exp(s/8), write Ps ----
#pragma unroll
        for (int r = 0; r < 4; ++r) {
            float p0 = __expf(s[0][r] * 0.125f);
            float p1 = __expf(s[1][r] * 0.125f);
            bf16_t b0 = (bf16_t)p0, b1 = (bf16_t)p1;
            lpart[r] += (float)b0 + (float)b1;
            Ps[wave][quad * 4 + r][l15]      = b0;
            Ps[wave][quad * 4 + r][16 + l15] = b1;
        }
        __syncthreads();   // B2: Ps(it) ready; Ks(it) reads done
        // ---- async-stage K(it+1) (lands during PV) ----
        if (it + 1 < FITERS) {
#pragma unroll
            for (int cc = 0; cc < 8; ++cc) {
                const int r = cc * 4 + wave;
                async_copy16(&qb[(size_t)(k0 + 32 + r) * 512 + lane * 8], &Ks[r][0]);
            }
        }
        // ---- PV: pa from Ps, bv DIRECT from global qt ----
        bf16x8 pa[4];
#pragma unroll
        for (int m = 0; m < 4; ++m)
            pa[m] = *(const bf16x8*)&Ps[m][l15][quad * 8];
#pragma unroll
        for (int n = 0; n < 8; ++n) {
            bf16x8 bv = *(const bf16x8*)&qtb[(size_t)(wave * 128 + n * 16 + l15) * 4096 + k0 + quad * 8];
#pragma unroll
            for (int m = 0; m < 4; ++m)
                O[m][n] = __builtin_amdgcn_mfma_f32_16x16x32_bf16(pa[m], bv, O[m][n], 0, 0, 0);
        }
    }

    // row exp-sums
#pragma unroll
    for (int r = 0; r < 4; ++r) {
        float ls = lpart[r];
#pragma unroll
        for (int d = 1; d < 16; d <<= 1) ls += __shfl_xor(ls, d);
        if (l15 == 0)
            atomicAdd(&Lacc_g[batch * SEQ + q0 + wave * 16 + quad * 4 + r], ls);
    }
    // unnormalized O -> out
#pragma unroll
    for (int m = 0; m < 4; ++m)
#pragma unroll
        for (int r = 0; r < 4; ++r) {
            const size_t row = (size_t)batch * SEQ + q0 + m * 16 + quad * 4 + r;
#pragma unroll
            for (int n = 0; n < 8; ++n)
                atomicAdd(&out[row * 512 + wave * 128 + n * 16 + l15], O[m][n][r]);
        }
}

// out[row][e] /= Lacc_g[row]
__global__ __launch_bounds__(256) void norm_kernel(float* __restrict__ out)
{
    const int idx = blockIdx.x * 256 + threadIdx.x;   // float4 index
    float4 v = ((float4*)out)[idx];
    const float inv = 1.0f / Lacc_g[idx >> 7];
    v.x *= inv; v.y *= inv; v.z *= inv; v.w *= inv;
    ((float4*)out)[idx] = v;
}

extern "C" void kernel_launch(void* const* d_in, const int* in_sizes, int n_in,
                              void* d_out, int out_size, void* d_ws, size_t ws_size,
                              hipStream_t stream) {
    const float* x     = (const float*)d_in[0];
    const float* theta = (const float*)d_in[1];
    const float* W     = (const float*)d_in[2];
    const float* bias  = (const float*)d_in[3];
    float* out   = (float*)d_out;
    bf16_t* qrow = (bf16_t*)d_ws;                       // [16384][512] bf16
    bf16_t* qt   = qrow + (size_t)MTOT * EMBED;         // [4][512][4096] bf16

    hipMemsetAsync(out, 0, (size_t)MTOT * EMBED * sizeof(float), stream);

    cvt_w_kernel<<<dim3(EMBED * EMBED / 4 / 256), dim3(256), 0, stream>>>(W);

    gemm_q_kernel<<<dim3(MTOT / 32), dim3(256), 0, stream>>>(x, theta, bias, qrow, qt);

    flash_kernel<<<dim3(64 * BATCH * NSPLIT), dim3(256), 0, stream>>>(qrow, qt, out);

    norm_kernel<<<dim3(MTOT * EMBED / 4 / 256), dim3(256), 0, stream>>>(out);
}